// Round 1
// baseline (3382.361 us; speedup 1.0000x reference)
//
#include <hip/hip_runtime.h>
#include <math.h>

// Problem constants
#define BB   16
#define NCC  64   // cells
#define NN   256  // neurons per cell
#define DD   64   // feature dim
#define AA   4
#define PP   4
#define GHH  8
#define GWW  8
#define HSS  256  // state hidden
#define HMM  256  // msg hidden

__device__ __forceinline__ float sigm(float v) { return 1.0f / (1.0f + expf(-v)); }

// One block per (b, c). 256 threads = 4 waves.
// LDS: s_recv 256x65, s_buf 64x257 (msg then hid chunks), s_hn 64x65 (h then h_new), small bufs.
extern "C" __global__ void __launch_bounds__(256)
mg_fused(const float* __restrict__ x, const float* __restrict__ h,
         const float* __restrict__ msg, const float* __restrict__ W,
         const float* __restrict__ decay_logit, const float* __restrict__ cell_context,
         const float* __restrict__ border_gate_logit, const float* __restrict__ neuron_id,
         const float* __restrict__ state_w1, const float* __restrict__ state_b1,
         const float* __restrict__ state_w2, const float* __restrict__ state_b2,
         const float* __restrict__ msg_w1, const float* __restrict__ msg_b1,
         const float* __restrict__ msg_w2, const float* __restrict__ msg_b2,
         const float* __restrict__ inject_w, const float* __restrict__ inject_b,
         const float* __restrict__ mod_w1, const float* __restrict__ mod_b1,
         const float* __restrict__ mod_w2, const float* __restrict__ mod_b2,
         const int* __restrict__ cell_to_group,
         float* __restrict__ out_read, float* __restrict__ out_h,
         float* __restrict__ out_msg)
{
    __shared__ float s_recv[NN * 65];      // received, padded rows (stride 65 -> 2-way banks, free)
    __shared__ float s_buf[64 * 257];      // phase1: msg[256][64]; phase2: hid tile [64][257]
    __shared__ float s_hn[64 * 65];        // h tile, then h_new tile
    __shared__ float s_cc[64], s_x[64], s_hmod[64], s_mod[8];
    __shared__ float s_decay[NN], s_bgate[4], s_mn[4 * 64];

    const int tid  = threadIdx.x;
    const int lane = tid & 63;
    const int qu   = __builtin_amdgcn_readfirstlane(tid >> 6);  // wave id, provably uniform
    const int bc   = blockIdx.x;
    const int b    = bc >> 6;
    const int c    = bc & 63;

    // ---------------- Phase 0: mod MLP -> decay, bgate; stage cc & x ----------------
    if (tid < 64) {
        s_cc[tid] = cell_context[bc * DD + tid];
        s_x[tid]  = x[(size_t)b * (NCC * DD) + c * DD + tid];
    }
    __syncthreads();
    if (tid < 64) {
        float acc = mod_b1[c * 64 + tid];
        const float* wp = mod_w1 + (size_t)c * 64 * 64 + tid;  // [(c*64+d)*64 + tid]
        #pragma unroll
        for (int d = 0; d < 64; ++d) acc += s_cc[d] * wp[d * 64];
        s_hmod[tid] = tanhf(acc);
    }
    __syncthreads();
    if (tid < 5) {
        float acc = mod_b2[c * 5 + tid];
        const float* wp = mod_w2 + (size_t)c * 64 * 5 + tid;
        #pragma unroll
        for (int hh = 0; hh < 64; ++hh) acc += s_hmod[hh] * wp[hh * 5];
        s_mod[tid] = acc;
    }
    __syncthreads();
    s_decay[tid] = sigm(decay_logit[(size_t)bc * NN + tid] + s_mod[0]);
    if (tid < 4) s_bgate[tid] = sigm(border_gate_logit[bc * 4 + tid] + s_mod[1 + tid]);

    // ---------------- Phase 1: stage msg; received = W @ msg ----------------
    {
        const float4* msrc = (const float4*)(msg + (size_t)bc * NN * DD);
        float4* mdst = (float4*)s_buf;     // msg stored [m][d], contiguous 256*64
        for (int i = tid; i < NN * DD / 4; i += 256) mdst[i] = msrc[i];
    }
    __syncthreads();
    {
        const float* Wb = W + (size_t)bc * NN * NN;
        for (int nn = 0; nn < 16; ++nn) {
            const int n0 = qu * 64 + nn * 4;
            const float4* w0 = (const float4*)(Wb + (size_t)(n0 + 0) * NN);
            const float4* w1 = (const float4*)(Wb + (size_t)(n0 + 1) * NN);
            const float4* w2 = (const float4*)(Wb + (size_t)(n0 + 2) * NN);
            const float4* w3 = (const float4*)(Wb + (size_t)(n0 + 3) * NN);
            float a0 = 0.f, a1 = 0.f, a2 = 0.f, a3 = 0.f;
            for (int m4 = 0; m4 < 64; ++m4) {
                const float mv0 = s_buf[(m4 * 4 + 0) * 64 + lane];
                const float mv1 = s_buf[(m4 * 4 + 1) * 64 + lane];
                const float mv2 = s_buf[(m4 * 4 + 2) * 64 + lane];
                const float mv3 = s_buf[(m4 * 4 + 3) * 64 + lane];
                const float4 v0 = w0[m4], v1 = w1[m4], v2 = w2[m4], v3 = w3[m4];
                a0 += v0.x * mv0; a1 += v1.x * mv0; a2 += v2.x * mv0; a3 += v3.x * mv0;
                a0 += v0.y * mv1; a1 += v1.y * mv1; a2 += v2.y * mv1; a3 += v3.y * mv1;
                a0 += v0.z * mv2; a1 += v1.z * mv2; a2 += v2.z * mv2; a3 += v3.z * mv2;
                a0 += v0.w * mv3; a1 += v1.w * mv3; a2 += v2.w * mv3; a3 += v3.w * mv3;
            }
            s_recv[(n0 + 0) * 65 + lane] = a0;
            s_recv[(n0 + 1) * 65 + lane] = a1;
            s_recv[(n0 + 2) * 65 + lane] = a2;
            s_recv[(n0 + 3) * 65 + lane] = a3;
        }
    }
    __syncthreads();

    // injection into rows 0..3 : o = tid -> (n = qu, d = lane)
    {
        const int g = cell_to_group[c];
        float acc = inject_b[g * 256 + tid];
        const float4* wv = (const float4*)(inject_w + ((size_t)g * 256 + tid) * 64);
        #pragma unroll
        for (int i4 = 0; i4 < 16; ++i4) {
            const float4 v = wv[i4];
            acc += v.x * s_x[i4 * 4 + 0] + v.y * s_x[i4 * 4 + 1]
                 + v.z * s_x[i4 * 4 + 2] + v.w * s_x[i4 * 4 + 3];
        }
        s_recv[qu * 65 + lane] += acc;
    }
    // border exchange into rows 8..11 : p = qu, d = lane
    {
        const int gi = c >> 3, gj = c & 7;
        int cn = -1, ps = 0;
        if (qu == 0)      { if (gi > 0)       { cn = c - GWW; ps = 1; } }
        else if (qu == 1) { if (gi < GHH - 1) { cn = c + GWW; ps = 0; } }
        else if (qu == 2) { if (gj > 0)       { cn = c - 1;   ps = 3; } }
        else              { if (gj < GWW - 1) { cn = c + 1;   ps = 2; } }
        if (cn >= 0) {
            const float v = msg[(((size_t)b * NCC + cn) * NN + (2 * AA + ps)) * DD + lane];
            s_recv[(2 * AA + qu) * 65 + lane] += s_bgate[qu] * v;
        }
    }
    __syncthreads();

    // ---------------- Phase 2: neuron tiles of 64 through the MLP chain ----------------
    for (int t0 = 0; t0 < NN; t0 += 64) {
        // stage h tile rows [t0, t0+64) into s_hn [row][65]
        {
            const float* hb = h + ((size_t)bc * NN + t0) * DD;
            for (int i = tid; i < 1024; i += 256) {          // 1024 float4 chunks
                const int row = i >> 4, c4 = (i & 15) * 4;
                const float4 v = *(const float4*)(hb + row * DD + c4);
                float* dst = &s_hn[row * 65 + c4];
                dst[0] = v.x; dst[1] = v.y; dst[2] = v.z; dst[3] = v.w;
            }
        }
        __syncthreads();

        // per-thread register rows (row = t0+lane), statically indexed
        float rr[64], rh[64];
        #pragma unroll
        for (int d = 0; d < 64; ++d) rr[d] = s_recv[(t0 + lane) * 65 + d];
        #pragma unroll
        for (int d = 0; d < 64; ++d) rh[d] = s_hn[lane * 65 + d];

        // hid_s[r][hh] for hh in wave's quarter (64 values), written to s_buf[64][257]
        for (int k = 0; k < 64; ++k) {
            const int hh = qu * 64 + k;
            const float* wr = state_w1 + hh * 128;
            float a0 = state_b1[hh], a1 = 0.f, a2 = 0.f, a3 = 0.f;
            #pragma unroll
            for (int d = 0; d < 64; d += 4) {
                a0 += rr[d + 0] * wr[d + 0]; a1 += rr[d + 1] * wr[d + 1];
                a2 += rr[d + 2] * wr[d + 2]; a3 += rr[d + 3] * wr[d + 3];
            }
            const float* wh = wr + 64;
            #pragma unroll
            for (int d = 0; d < 64; d += 4) {
                a0 += rh[d + 0] * wh[d + 0]; a1 += rh[d + 1] * wh[d + 1];
                a2 += rh[d + 2] * wh[d + 2]; a3 += rh[d + 3] * wh[d + 3];
            }
            s_buf[lane * 257 + hh] = tanhf((a0 + a1) + (a2 + a3));
        }
        __syncthreads();

        // cand pre-act: cv[k] for d = qu*16+k
        float cv[16];
        #pragma unroll
        for (int k = 0; k < 16; ++k) cv[k] = state_b2[qu * 16 + k];
        for (int ch = 0; ch < 4; ++ch) {
            float rc[64];
            #pragma unroll
            for (int j = 0; j < 64; ++j) rc[j] = s_buf[lane * 257 + ch * 64 + j];
            #pragma unroll
            for (int k = 0; k < 16; ++k) {
                const float* wr = state_w2 + (qu * 16 + k) * 256 + ch * 64;
                float a0 = 0.f, a1 = 0.f, a2 = 0.f, a3 = 0.f;
                #pragma unroll
                for (int j = 0; j < 64; j += 4) {
                    a0 += rc[j + 0] * wr[j + 0]; a1 += rc[j + 1] * wr[j + 1];
                    a2 += rc[j + 2] * wr[j + 2]; a3 += rc[j + 3] * wr[j + 3];
                }
                cv[k] += (a0 + a1) + (a2 + a3);
            }
        }
        __syncthreads();   // done reading s_buf (hid_s)

        // h_new: read own h quarter from s_hn, blend, write back + global
        const float dec = s_decay[t0 + lane];
        float hnv[16];
        #pragma unroll
        for (int k = 0; k < 16; ++k) {
            const float hval = s_hn[lane * 65 + qu * 16 + k];
            hnv[k] = dec * hval + (1.0f - dec) * tanhf(cv[k]);
            s_hn[lane * 65 + qu * 16 + k] = hnv[k];
        }
        {
            float* op = out_h + ((size_t)bc * NN + t0 + lane) * DD + qu * 16;
            #pragma unroll
            for (int j = 0; j < 4; ++j)
                *(float4*)(op + 4 * j) = make_float4(hnv[4 * j + 0], hnv[4 * j + 1],
                                                     hnv[4 * j + 2], hnv[4 * j + 3]);
        }
        __syncthreads();   // h_new tile complete in s_hn

        // hid_m: full h_new row into regs, then same pattern as hid_s
        float hr[64];
        #pragma unroll
        for (int d = 0; d < 64; ++d) hr[d] = s_hn[lane * 65 + d];
        for (int k = 0; k < 64; ++k) {
            const int hh = qu * 64 + k;
            const float* wr = msg_w1 + hh * 64;
            float a0 = msg_b1[hh], a1 = 0.f, a2 = 0.f, a3 = 0.f;
            #pragma unroll
            for (int d = 0; d < 64; d += 4) {
                a0 += hr[d + 0] * wr[d + 0]; a1 += hr[d + 1] * wr[d + 1];
                a2 += hr[d + 2] * wr[d + 2]; a3 += hr[d + 3] * wr[d + 3];
            }
            s_buf[lane * 257 + hh] = tanhf((a0 + a1) + (a2 + a3));
        }
        __syncthreads();

        // msg_new pre-act
        float mvv[16];
        #pragma unroll
        for (int k = 0; k < 16; ++k) mvv[k] = msg_b2[qu * 16 + k];
        for (int ch = 0; ch < 4; ++ch) {
            float rc[64];
            #pragma unroll
            for (int j = 0; j < 64; ++j) rc[j] = s_buf[lane * 257 + ch * 64 + j];
            #pragma unroll
            for (int k = 0; k < 16; ++k) {
                const float* wr = msg_w2 + (qu * 16 + k) * 256 + ch * 64;
                float a0 = 0.f, a1 = 0.f, a2 = 0.f, a3 = 0.f;
                #pragma unroll
                for (int j = 0; j < 64; j += 4) {
                    a0 += rc[j + 0] * wr[j + 0]; a1 += rc[j + 1] * wr[j + 1];
                    a2 += rc[j + 2] * wr[j + 2]; a3 += rc[j + 3] * wr[j + 3];
                }
                mvv[k] += (a0 + a1) + (a2 + a3);
            }
        }
        // msg_new = tanh + neuron_id; write global; capture rows 4..7 for readout
        {
            const float4* nv = (const float4*)(neuron_id + ((size_t)c * NN + t0 + lane) * DD + qu * 16);
            float* op = out_msg + ((size_t)bc * NN + t0 + lane) * DD + qu * 16;
            #pragma unroll
            for (int j = 0; j < 4; ++j) {
                const float4 nid4 = nv[j];
                float4 o;
                o.x = tanhf(mvv[4 * j + 0]) + nid4.x;
                o.y = tanhf(mvv[4 * j + 1]) + nid4.y;
                o.z = tanhf(mvv[4 * j + 2]) + nid4.z;
                o.w = tanhf(mvv[4 * j + 3]) + nid4.w;
                *(float4*)(op + 4 * j) = o;
                if (t0 == 0 && lane >= AA && lane < 2 * AA) {
                    float* sp = &s_mn[(lane - AA) * 64 + qu * 16 + 4 * j];
                    sp[0] = o.x; sp[1] = o.y; sp[2] = o.z; sp[3] = o.w;
                }
            }
        }
        __syncthreads();   // protects s_buf/s_hn reuse next tile and s_mn
    }

    // readout = mean of msg_new rows 4..7
    if (tid < 64) {
        out_read[(size_t)b * (NCC * DD) + c * 64 + tid] =
            0.25f * (s_mn[tid] + s_mn[64 + tid] + s_mn[128 + tid] + s_mn[192 + tid]);
    }
}

extern "C" void kernel_launch(void* const* d_in, const int* in_sizes, int n_in,
                              void* d_out, int out_size, void* d_ws, size_t ws_size,
                              hipStream_t stream) {
    (void)in_sizes; (void)n_in; (void)d_ws; (void)ws_size; (void)out_size;
    const float* x                 = (const float*)d_in[0];
    const float* h                 = (const float*)d_in[1];
    const float* msg               = (const float*)d_in[2];
    const float* W                 = (const float*)d_in[3];
    const float* decay_logit       = (const float*)d_in[4];
    const float* cell_context      = (const float*)d_in[5];
    const float* border_gate_logit = (const float*)d_in[6];
    const float* neuron_id         = (const float*)d_in[7];
    const float* state_w1          = (const float*)d_in[8];
    const float* state_b1          = (const float*)d_in[9];
    const float* state_w2          = (const float*)d_in[10];
    const float* state_b2          = (const float*)d_in[11];
    const float* msg_w1            = (const float*)d_in[12];
    const float* msg_b1            = (const float*)d_in[13];
    const float* msg_w2            = (const float*)d_in[14];
    const float* msg_b2            = (const float*)d_in[15];
    const float* inject_w          = (const float*)d_in[16];
    const float* inject_b          = (const float*)d_in[17];
    const float* mod_w1            = (const float*)d_in[18];
    const float* mod_b1            = (const float*)d_in[19];
    const float* mod_w2            = (const float*)d_in[20];
    const float* mod_b2            = (const float*)d_in[21];
    const int*   cell_to_group     = (const int*)d_in[22];

    float* out_read = (float*)d_out;
    float* out_h    = out_read + (size_t)BB * NCC * DD;             // 65536
    float* out_msg  = out_h + (size_t)BB * NCC * NN * DD;           // +16777216

    hipLaunchKernelGGL(mg_fused, dim3(BB * NCC), dim3(256), 0, stream,
                       x, h, msg, W, decay_logit, cell_context, border_gate_logit,
                       neuron_id, state_w1, state_b1, state_w2, state_b2,
                       msg_w1, msg_b1, msg_w2, msg_b2, inject_w, inject_b,
                       mod_w1, mod_b1, mod_w2, mod_b2, cell_to_group,
                       out_read, out_h, out_msg);
}

// Round 2
// 500.203 us; speedup vs baseline: 6.7620x; 6.7620x over previous
//
#include <hip/hip_runtime.h>
#include <math.h>

#define BB 16
#define NCC 64
#define NN 256
#define DD 64

typedef short s16x8 __attribute__((ext_vector_type(8)));
typedef float f32x4 __attribute__((ext_vector_type(4)));

#define MFMA16(a, b, c) __builtin_amdgcn_mfma_f32_16x16x32_bf16((a), (b), (c), 0, 0, 0)

__device__ __forceinline__ unsigned short f2bf(float f) {
    union { float f; unsigned u; } v; v.f = f;
    unsigned r = v.u + 0x7FFFu + ((v.u >> 16) & 1u);   // RNE
    return (unsigned short)(r >> 16);
}
__device__ __forceinline__ float bf2f(unsigned short s) {
    union { unsigned u; float f; } v; v.u = ((unsigned)s) << 16;
    return v.f;
}
__device__ __forceinline__ float sigm(float v) { return 1.0f / (1.0f + expf(-v)); }

__device__ __forceinline__ s16x8 pack8(float4 lo, float4 hi) {
    s16x8 r;
    r[0] = (short)f2bf(lo.x); r[1] = (short)f2bf(lo.y);
    r[2] = (short)f2bf(lo.z); r[3] = (short)f2bf(lo.w);
    r[4] = (short)f2bf(hi.x); r[5] = (short)f2bf(hi.y);
    r[6] = (short)f2bf(hi.z); r[7] = (short)f2bf(hi.w);
    return r;
}

// ---------------- weight f32 -> bf16 prep (tiny, runs every call) ----------------
// ws layout (elems): sw1[32768] | sw2[16384] | mw1[16384] | mw2[16384]
extern "C" __global__ void __launch_bounds__(256)
wconv(const float* __restrict__ sw1, const float* __restrict__ sw2,
      const float* __restrict__ mw1, const float* __restrict__ mw2,
      unsigned short* __restrict__ ws)
{
    const int i = blockIdx.x * 256 + threadIdx.x;
    float v;
    if (i < 32768)      v = sw1[i];
    else if (i < 49152) v = sw2[i - 32768];
    else if (i < 65536) v = mw1[i - 49152];
    else                v = mw2[i - 65536];
    ws[i] = f2bf(v);
}

// ---------------- fused main kernel: one block per (b,c), 512 threads ----------------
// LDS pitches: recv/h rows pitch 72 bf16 (144B: 2-way banks, 16B aligned);
// msgT/hid rows pitch 264 bf16 (528B: 2-way banks, 16B aligned).
extern "C" __global__ void __launch_bounds__(512, 2)
mg_mfma(const float* __restrict__ x, const float* __restrict__ h,
        const float* __restrict__ msg, const float* __restrict__ W,
        const float* __restrict__ decay_logit, const float* __restrict__ cell_context,
        const float* __restrict__ border_gate_logit, const float* __restrict__ neuron_id,
        const float* __restrict__ state_b1, const float* __restrict__ state_b2,
        const float* __restrict__ msg_b1, const float* __restrict__ msg_b2,
        const float* __restrict__ inject_w, const float* __restrict__ inject_b,
        const float* __restrict__ mod_w1, const float* __restrict__ mod_b1,
        const float* __restrict__ mod_w2, const float* __restrict__ mod_b2,
        const int* __restrict__ cell_to_group,
        const unsigned short* __restrict__ sw1b, const unsigned short* __restrict__ sw2b,
        const unsigned short* __restrict__ mw1b, const unsigned short* __restrict__ mw2b,
        float* __restrict__ out_read, float* __restrict__ out_h, float* __restrict__ out_msg)
{
    // s_pool aliases: msgT [64][264] during phase A, hid tile [64][264] afterwards
    __shared__ __align__(16) unsigned short s_pool[64 * 264];   // 33792 B
    __shared__ __align__(16) unsigned short s_recv[256 * 72];   // 36864 B (full recv, bf16)
    __shared__ __align__(16) unsigned short s_h[64 * 72];       //  9216 B (h tile -> h_new tile)
    __shared__ float s_x[64], s_cc[64], s_hmod[64], s_mod[8];
    __shared__ float s_decay[256], s_bgate[4];
    __shared__ float s_inj[256], s_bord[256], s_mn[256];

    unsigned short* const s_msgT = s_pool;
    unsigned short* const s_hid  = s_pool;

    const int tid  = threadIdx.x;
    const int lane = tid & 63;
    const int l15  = lane & 15;
    const int g    = lane >> 4;                                  // quarter-wave 0..3
    const int wid  = __builtin_amdgcn_readfirstlane(tid >> 6);   // wave 0..7
    const int bc   = blockIdx.x;
    const int b    = bc >> 6;
    const int c    = bc & 63;

    // ---------------- Phase 0: mod MLP, decay/bgate, inject dots, border gather ----------------
    if (tid < 64) {
        s_cc[tid] = cell_context[bc * DD + tid];
        s_x[tid]  = x[(size_t)b * (NCC * DD) + c * DD + tid];
    }
    __syncthreads();
    if (tid < 64) {
        float acc = mod_b1[c * 64 + tid];
        const float* wp = mod_w1 + (size_t)c * 64 * 64 + tid;
        #pragma unroll
        for (int d = 0; d < 64; ++d) acc += s_cc[d] * wp[d * 64];
        s_hmod[tid] = tanhf(acc);
    }
    __syncthreads();
    if (tid < 5) {
        float acc = mod_b2[c * 5 + tid];
        const float* wp = mod_w2 + (size_t)c * 64 * 5 + tid;
        #pragma unroll
        for (int hh = 0; hh < 64; ++hh) acc += s_hmod[hh] * wp[hh * 5];
        s_mod[tid] = acc;
    }
    __syncthreads();
    if (tid < 256) {
        s_decay[tid] = sigm(decay_logit[(size_t)bc * NN + tid] + s_mod[0]);
        if (tid < 4) s_bgate[tid] = sigm(border_gate_logit[bc * 4 + tid] + s_mod[1 + tid]);
        // inject: o = tid (n = tid>>6 in 0..3, d = tid&63)
        const int grp = cell_to_group[c];
        float acc = inject_b[grp * 256 + tid];
        const float4* wv = (const float4*)(inject_w + ((size_t)grp * 256 + tid) * 64);
        #pragma unroll
        for (int i4 = 0; i4 < 16; ++i4) {
            const float4 v = wv[i4];
            acc += v.x * s_x[i4 * 4 + 0] + v.y * s_x[i4 * 4 + 1]
                 + v.z * s_x[i4 * 4 + 2] + v.w * s_x[i4 * 4 + 3];
        }
        s_inj[tid] = acc;
    } else {
        // border gather: q = tid-256, p = q>>6, d = q&63
        const int q = tid - 256, p = q >> 6, d = q & 63;
        const int gi = c >> 3, gj = c & 7;
        int cn = -1, ps = 0;
        if (p == 0)      { if (gi > 0) { cn = c - 8; ps = 1; } }
        else if (p == 1) { if (gi < 7) { cn = c + 8; ps = 0; } }
        else if (p == 2) { if (gj > 0) { cn = c - 1; ps = 3; } }
        else             { if (gj < 7) { cn = c + 1; ps = 2; } }
        s_bord[q] = (cn >= 0) ? msg[(((size_t)b * NCC + cn) * NN + 8 + ps) * DD + d] : 0.0f;
    }

    // ---------------- msg -> LDS transposed bf16 (msgT[d][m], pitch 264) ----------------
    for (int it = tid; it < 2048; it += 512) {
        const int d4 = it & 15, mp = it >> 4;           // mp: 0..127 -> m pair
        const float* src = msg + ((size_t)bc * NN + mp * 2) * DD + d4 * 4;
        const float4 v0 = *(const float4*)(src);
        const float4 v1 = *(const float4*)(src + DD);
        const float* p0 = &v0.x; const float* p1 = &v1.x;
        #pragma unroll
        for (int j = 0; j < 4; ++j) {
            const unsigned pk = (unsigned)f2bf(p0[j]) | ((unsigned)f2bf(p1[j]) << 16);
            *(unsigned*)&s_msgT[(d4 * 4 + j) * 264 + mp * 2] = pk;
        }
    }
    __syncthreads();

    // ---------------- Phase A: recv = W @ msg (full 256 rows, uninterrupted W stream) ----------------
    {
        const int r0 = wid * 32 + l15;                  // wave covers rows [wid*32, wid*32+32)
        const float* W0 = W + ((size_t)bc * NN + r0) * NN;
        const float* W1 = W0 + 16 * NN;
        f32x4 acc[2][4];
        #pragma unroll
        for (int rt = 0; rt < 2; ++rt)
            #pragma unroll
            for (int ct = 0; ct < 4; ++ct) acc[rt][ct] = f32x4{0.f, 0.f, 0.f, 0.f};
        #pragma unroll
        for (int k = 0; k < 8; ++k) {
            const int ko = 32 * k + 8 * g;
            const float4 a0l = *(const float4*)(W0 + ko);
            const float4 a0h = *(const float4*)(W0 + ko + 4);
            const float4 a1l = *(const float4*)(W1 + ko);
            const float4 a1h = *(const float4*)(W1 + ko + 4);
            const s16x8 af0 = pack8(a0l, a0h);
            const s16x8 af1 = pack8(a1l, a1h);
            #pragma unroll
            for (int ct = 0; ct < 4; ++ct) {
                const s16x8 bf = *(const s16x8*)&s_msgT[(ct * 16 + l15) * 264 + ko];
                acc[0][ct] = MFMA16(af0, bf, acc[0][ct]);
                acc[1][ct] = MFMA16(af1, bf, acc[1][ct]);
            }
        }
        #pragma unroll
        for (int rt = 0; rt < 2; ++rt)
            #pragma unroll
            for (int ct = 0; ct < 4; ++ct)
                #pragma unroll
                for (int i = 0; i < 4; ++i) {
                    const int row = wid * 32 + rt * 16 + g * 4 + i;  // C: row=(l>>4)*4+i, col=l&15
                    s_recv[row * 72 + ct * 16 + l15] = f2bf(acc[rt][ct][i]);
                }
    }
    __syncthreads();

    // edits: inject rows 0..3, gated border rows 8..11
    if (tid < 256) {
        const int n = tid >> 6, d = tid & 63;
        const float v1 = bf2f(s_recv[n * 72 + d]) + s_inj[tid];
        s_recv[n * 72 + d] = f2bf(v1);
        const float v2 = bf2f(s_recv[(8 + n) * 72 + d]) + s_bgate[n] * s_bord[tid];
        s_recv[(8 + n) * 72 + d] = f2bf(v2);
    }
    __syncthreads();

    // ---------------- Tiles of 64 rows through the MLP chain (MFMA) ----------------
    for (int t = 0; t < 4; ++t) {
        const int mbase = t * 64;

        // stage h tile -> s_h bf16 [64][72]
        for (int it = tid; it < 1024; it += 512) {
            const int row = it >> 4, d4 = it & 15;
            const float4 v = *(const float4*)(h + ((size_t)bc * NN + mbase + row) * DD + d4 * 4);
            unsigned short* dst = &s_h[row * 72 + d4 * 4];
            *(unsigned*)(dst)     = (unsigned)f2bf(v.x) | ((unsigned)f2bf(v.y) << 16);
            *(unsigned*)(dst + 2) = (unsigned)f2bf(v.z) | ((unsigned)f2bf(v.w) << 16);
        }
        __syncthreads();

        // Phase B: hid_s = tanh([recv|h] @ sw1^T + b1)   (K=128, out [64][256])
        {
            const int rt = wid >> 1, ctb = (wid & 1) * 8;
            const int ar = (mbase + rt * 16 + l15) * 72;
            const int hr = (rt * 16 + l15) * 72;
            const s16x8 a0 = *(const s16x8*)&s_recv[ar + 8 * g];
            const s16x8 a1 = *(const s16x8*)&s_recv[ar + 32 + 8 * g];
            const s16x8 a2 = *(const s16x8*)&s_h[hr + 8 * g];
            const s16x8 a3 = *(const s16x8*)&s_h[hr + 32 + 8 * g];
            #pragma unroll
            for (int cc = 0; cc < 8; ++cc) {
                const int n0 = (ctb + cc) * 16;
                const unsigned short* Bb = sw1b + (size_t)(n0 + l15) * 128;
                f32x4 acc = f32x4{0.f, 0.f, 0.f, 0.f};
                acc = MFMA16(a0, *(const s16x8*)(Bb + 8 * g), acc);
                acc = MFMA16(a1, *(const s16x8*)(Bb + 32 + 8 * g), acc);
                acc = MFMA16(a2, *(const s16x8*)(Bb + 64 + 8 * g), acc);
                acc = MFMA16(a3, *(const s16x8*)(Bb + 96 + 8 * g), acc);
                const float bias = state_b1[n0 + l15];
                #pragma unroll
                for (int i = 0; i < 4; ++i)
                    s_hid[(rt * 16 + g * 4 + i) * 264 + n0 + l15] = f2bf(tanhf(acc[i] + bias));
            }
        }
        __syncthreads();

        // Phase C: cand = tanh(hid_s @ sw2^T + b2); h_new = d*h + (1-d)*cand  (K=256, out [64][64])
        {
            const int rt = wid >> 1, ct0 = (wid & 1) * 2;
            const unsigned short* Ar = &s_hid[(rt * 16 + l15) * 264];
            const unsigned short* B0 = sw2b + (size_t)(ct0 * 16 + l15) * 256;
            const unsigned short* B1 = B0 + 16 * 256;
            f32x4 acc0 = f32x4{0.f, 0.f, 0.f, 0.f}, acc1 = f32x4{0.f, 0.f, 0.f, 0.f};
            #pragma unroll
            for (int k = 0; k < 8; ++k) {
                const int ko = 32 * k + 8 * g;
                const s16x8 af = *(const s16x8*)(Ar + ko);
                acc0 = MFMA16(af, *(const s16x8*)(B0 + ko), acc0);
                acc1 = MFMA16(af, *(const s16x8*)(B1 + ko), acc1);
            }
            const int d0 = ct0 * 16 + l15, d1 = d0 + 16;
            const float sb0 = state_b2[d0], sb1 = state_b2[d1];
            #pragma unroll
            for (int i = 0; i < 4; ++i) {
                const int lrow = rt * 16 + g * 4 + i;
                const int grow = mbase + lrow;
                const float dec = s_decay[grow];
                const float h0 = bf2f(s_h[lrow * 72 + d0]);
                const float h1 = bf2f(s_h[lrow * 72 + d1]);
                const float hn0 = dec * h0 + (1.f - dec) * tanhf(acc0[i] + sb0);
                const float hn1 = dec * h1 + (1.f - dec) * tanhf(acc1[i] + sb1);
                s_h[lrow * 72 + d0] = f2bf(hn0);     // element-exclusive in-place update
                s_h[lrow * 72 + d1] = f2bf(hn1);
                float* op = out_h + ((size_t)bc * NN + grow) * DD;
                op[d0] = hn0; op[d1] = hn1;
            }
        }
        __syncthreads();

        // Phase D: hid_m = tanh(h_new @ mw1^T + b1m)  (K=64, out [64][256])
        {
            const int rt = wid >> 1, ctb = (wid & 1) * 8;
            const int hr = (rt * 16 + l15) * 72;
            const s16x8 a0 = *(const s16x8*)&s_h[hr + 8 * g];
            const s16x8 a1 = *(const s16x8*)&s_h[hr + 32 + 8 * g];
            #pragma unroll
            for (int cc = 0; cc < 8; ++cc) {
                const int n0 = (ctb + cc) * 16;
                const unsigned short* Bb = mw1b + (size_t)(n0 + l15) * 64;
                f32x4 acc = f32x4{0.f, 0.f, 0.f, 0.f};
                acc = MFMA16(a0, *(const s16x8*)(Bb + 8 * g), acc);
                acc = MFMA16(a1, *(const s16x8*)(Bb + 32 + 8 * g), acc);
                const float bias = msg_b1[n0 + l15];
                #pragma unroll
                for (int i = 0; i < 4; ++i)
                    s_hid[(rt * 16 + g * 4 + i) * 264 + n0 + l15] = f2bf(tanhf(acc[i] + bias));
            }
        }
        __syncthreads();

        // Phase E: msg_new = tanh(hid_m @ mw2^T + b2m) + neuron_id  (K=256, out [64][64])
        {
            const int rt = wid >> 1, ct0 = (wid & 1) * 2;
            const unsigned short* Ar = &s_hid[(rt * 16 + l15) * 264];
            const unsigned short* B0 = mw2b + (size_t)(ct0 * 16 + l15) * 256;
            const unsigned short* B1 = B0 + 16 * 256;
            f32x4 acc0 = f32x4{0.f, 0.f, 0.f, 0.f}, acc1 = f32x4{0.f, 0.f, 0.f, 0.f};
            #pragma unroll
            for (int k = 0; k < 8; ++k) {
                const int ko = 32 * k + 8 * g;
                const s16x8 af = *(const s16x8*)(Ar + ko);
                acc0 = MFMA16(af, *(const s16x8*)(B0 + ko), acc0);
                acc1 = MFMA16(af, *(const s16x8*)(B1 + ko), acc1);
            }
            const int d0 = ct0 * 16 + l15, d1 = d0 + 16;
            const float mb0 = msg_b2[d0], mb1 = msg_b2[d1];
            #pragma unroll
            for (int i = 0; i < 4; ++i) {
                const int lrow = rt * 16 + g * 4 + i;
                const int grow = mbase + lrow;
                const float* nid = neuron_id + ((size_t)c * NN + grow) * DD;
                const float m0 = tanhf(acc0[i] + mb0) + nid[d0];
                const float m1 = tanhf(acc1[i] + mb1) + nid[d1];
                float* op = out_msg + ((size_t)bc * NN + grow) * DD;
                op[d0] = m0; op[d1] = m1;
                if (t == 0 && grow >= 4 && grow < 8) {
                    s_mn[(grow - 4) * 64 + d0] = m0;
                    s_mn[(grow - 4) * 64 + d1] = m1;
                }
            }
        }
        __syncthreads();
    }

    // readout = mean of msg_new rows 4..7
    if (tid < 64) {
        out_read[(size_t)b * (NCC * DD) + c * 64 + tid] =
            0.25f * (s_mn[tid] + s_mn[64 + tid] + s_mn[128 + tid] + s_mn[192 + tid]);
    }
}

extern "C" void kernel_launch(void* const* d_in, const int* in_sizes, int n_in,
                              void* d_out, int out_size, void* d_ws, size_t ws_size,
                              hipStream_t stream) {
    (void)in_sizes; (void)n_in; (void)ws_size; (void)out_size;
    const float* x                 = (const float*)d_in[0];
    const float* h                 = (const float*)d_in[1];
    const float* msg               = (const float*)d_in[2];
    const float* W                 = (const float*)d_in[3];
    const float* decay_logit       = (const float*)d_in[4];
    const float* cell_context      = (const float*)d_in[5];
    const float* border_gate_logit = (const float*)d_in[6];
    const float* neuron_id         = (const float*)d_in[7];
    const float* state_w1          = (const float*)d_in[8];
    const float* state_b1          = (const float*)d_in[9];
    const float* state_w2          = (const float*)d_in[10];
    const float* state_b2          = (const float*)d_in[11];
    const float* msg_w1            = (const float*)d_in[12];
    const float* msg_b1            = (const float*)d_in[13];
    const float* msg_w2            = (const float*)d_in[14];
    const float* msg_b2            = (const float*)d_in[15];
    const float* inject_w          = (const float*)d_in[16];
    const float* inject_b          = (const float*)d_in[17];
    const float* mod_w1            = (const float*)d_in[18];
    const float* mod_b1            = (const float*)d_in[19];
    const float* mod_w2            = (const float*)d_in[20];
    const float* mod_b2            = (const float*)d_in[21];
    const int*   cell_to_group     = (const int*)d_in[22];

    float* out_read = (float*)d_out;
    float* out_h    = out_read + (size_t)BB * NCC * DD;
    float* out_msg  = out_h + (size_t)BB * NCC * NN * DD;

    unsigned short* ws   = (unsigned short*)d_ws;
    unsigned short* sw1b = ws;
    unsigned short* sw2b = ws + 32768;
    unsigned short* mw1b = ws + 49152;
    unsigned short* mw2b = ws + 65536;

    hipLaunchKernelGGL(wconv, dim3(320), dim3(256), 0, stream,
                       state_w1, state_w2, msg_w1, msg_w2, ws);

    hipLaunchKernelGGL(mg_mfma, dim3(BB * NCC), dim3(512), 0, stream,
                       x, h, msg, W, decay_logit, cell_context, border_gate_logit,
                       neuron_id, state_b1, state_b2, msg_b1, msg_b2,
                       inject_w, inject_b, mod_w1, mod_b1, mod_w2, mod_b2,
                       cell_to_group, sw1b, sw2b, mw1b, mw2b,
                       out_read, out_h, out_msg);
}

// Round 4
// 256.607 us; speedup vs baseline: 13.1811x; 1.9493x over previous
//
#include <hip/hip_runtime.h>
#include <math.h>

#define BB 16
#define NCC 64
#define NN 256
#define DD 64

typedef short s16x8 __attribute__((ext_vector_type(8)));
typedef float f32x4 __attribute__((ext_vector_type(4)));

#define MFMA16(a,b,c) __builtin_amdgcn_mfma_f32_16x16x32_bf16((a),(b),(c),0,0,0)

__device__ __forceinline__ unsigned short f2bf(float f){
    union{float f;unsigned u;}v; v.f=f;
    unsigned r = v.u + 0x7FFFu + ((v.u>>16)&1u);   // RNE
    return (unsigned short)(r>>16);
}
__device__ __forceinline__ float bf2f(unsigned short s){
    union{unsigned u;float f;}v; v.u=((unsigned)s)<<16; return v.f;
}
// v_cvt_pk_bf16_f32: no builtin on gfx950 (T12 recipe) -> inline asm
__device__ __forceinline__ unsigned cvt2(float a,float b){
    unsigned r;
    asm("v_cvt_pk_bf16_f32 %0, %1, %2" : "=v"(r) : "v"(a), "v"(b));
    return r;
}
__device__ __forceinline__ s16x8 pack8(float4 lo,float4 hi){
    union{unsigned u[4];s16x8 v;}r;
    r.u[0]=cvt2(lo.x,lo.y); r.u[1]=cvt2(lo.z,lo.w);
    r.u[2]=cvt2(hi.x,hi.y); r.u[3]=cvt2(hi.z,hi.w);
    return r.v;
}
__device__ __forceinline__ float tanh_fast(float xx){
    float x = fminf(15.0f,fmaxf(-15.0f,xx));
    float e = __expf(2.0f*x);                      // v_mul + v_exp_f32
    return (e-1.0f)*__builtin_amdgcn_rcpf(e+1.0f); // abs err ~1e-6 << bf16 noise
}
__device__ __forceinline__ float sigm(float v){ return __builtin_amdgcn_rcpf(1.0f+__expf(-v)); }

// ---------------- weight f32 -> bf16 prep ----------------
// ws (ushort elems): sw1b[32768] | sw2b[16384] | mw1b[16384] | mw2b[16384]
extern "C" __global__ void __launch_bounds__(256)
wconv(const float* __restrict__ sw1, const float* __restrict__ sw2,
      const float* __restrict__ mw1, const float* __restrict__ mw2,
      unsigned short* __restrict__ ws)
{
    const int i = blockIdx.x * 256 + threadIdx.x;
    float v;
    if (i < 32768)      v = sw1[i];
    else if (i < 49152) v = sw2[i - 32768];
    else if (i < 65536) v = mw1[i - 49152];
    else                v = mw2[i - 65536];
    ws[i] = f2bf(v);
}

// ---------------- Kernel A: recv = W@msg (+ mod MLP, inject, border edits) ----------------
// One block per (b,c), 512 threads. W streamed via global_load_lds double-buffer,
// counted vmcnt(4) + raw s_barrier (m201 pattern). recv -> ws as bf16.
extern "C" __global__ void __launch_bounds__(512,2)
mg_recv(const float* __restrict__ x, const float* __restrict__ msg,
        const float* __restrict__ W, const float* __restrict__ decay_logit,
        const float* __restrict__ cell_context, const float* __restrict__ border_gate_logit,
        const float* __restrict__ inject_w, const float* __restrict__ inject_b,
        const float* __restrict__ mod_w1, const float* __restrict__ mod_b1,
        const float* __restrict__ mod_w2, const float* __restrict__ mod_b2,
        const int* __restrict__ cell_to_group,
        unsigned short* __restrict__ ws_recv, float* __restrict__ ws_decay)
{
    __shared__ __align__(16) float s_w[2][32*260];            // 66560 B, pitch 260 f32
    __shared__ __align__(16) unsigned short s_msgT[64*264];   // 33792 B
    __shared__ float s_x[64], s_cc[64], s_hmod[64], s_mod[8], s_bgate[4];
    __shared__ float s_inj[256], s_bord[256];

    const int tid  = threadIdx.x;
    const int lane = tid & 63;
    const int l15  = lane & 15;
    const int g    = lane >> 4;
    const int wid  = __builtin_amdgcn_readfirstlane(tid >> 6);
    const int bc   = blockIdx.x;
    const int b    = bc >> 6;
    const int c    = bc & 63;
    const float* Wb = W + (size_t)bc * NN * NN;

#define STAGE_CHUNK(n) do{                                                            \
    const int _buf=(n)&1;                                                             \
    _Pragma("unroll")                                                                 \
    for(int _j=0;_j<4;++_j){                                                          \
        const int _row=4*wid+_j;                                                      \
        const float* _gp = Wb + (size_t)(32*(n)+_row)*NN + lane*4;                    \
        __builtin_amdgcn_global_load_lds(                                             \
            (const __attribute__((address_space(1))) void*)_gp,                       \
            (__attribute__((address_space(3))) void*)&s_w[_buf][_row*260], 16, 0, 0); \
    }                                                                                 \
}while(0)

    // deep-queue prefetch of W chunks 0 and 1 (8 x 1KB wave-loads in flight)
    STAGE_CHUNK(0);
    STAGE_CHUNK(1);

    // msg -> LDS transposed bf16 (msgT[d][m], pitch 264) -- overlaps W flight
    for (int it = tid; it < 2048; it += 512) {
        const int d4 = it & 15, mp = it >> 4;
        const float* src = msg + ((size_t)bc * NN + mp * 2) * DD + d4 * 4;
        const float4 v0 = *(const float4*)(src);
        const float4 v1 = *(const float4*)(src + DD);
        const float* p0 = &v0.x; const float* p1 = &v1.x;
        #pragma unroll
        for (int j = 0; j < 4; ++j)
            *(unsigned*)&s_msgT[(d4 * 4 + j) * 264 + mp * 2] = cvt2(p0[j], p1[j]);
    }

    asm volatile("s_waitcnt lgkmcnt(0)" ::: "memory");
    __builtin_amdgcn_sched_barrier(0);
    __builtin_amdgcn_s_barrier();          // msgT visible to all waves
    __builtin_amdgcn_sched_barrier(0);

    const int rt = wid & 1, ct = wid >> 1;
    for (int rc = 0; rc < 8; ++rc) {
        if (rc >= 1 && rc <= 6) STAGE_CHUNK(rc + 1);
        if (rc < 7) asm volatile("s_waitcnt vmcnt(4)" ::: "memory");
        else        asm volatile("s_waitcnt vmcnt(0)" ::: "memory");
        __builtin_amdgcn_sched_barrier(0);
        __builtin_amdgcn_s_barrier();      // chunk rc landed (all waves)
        __builtin_amdgcn_sched_barrier(0);
        {
            const float* wrow = &s_w[rc & 1][(16 * rt + l15) * 260];
            const unsigned short* brow = &s_msgT[(16 * ct + l15) * 264];
            f32x4 acc = {0.f, 0.f, 0.f, 0.f};
            #pragma unroll
            for (int k = 0; k < 8; ++k) {
                const float4 w0 = *(const float4*)(wrow + 32 * k + 8 * g);
                const float4 w1 = *(const float4*)(wrow + 32 * k + 8 * g + 4);
                const s16x8 bf = *(const s16x8*)(brow + 32 * k + 8 * g);
                acc = MFMA16(pack8(w0, w1), bf, acc);
            }
            const int rowb = 32 * rc + 16 * rt + 4 * g;
            unsigned short* op = ws_recv + ((size_t)bc * NN + rowb) * DD + 16 * ct + l15;
            #pragma unroll
            for (int i = 0; i < 4; ++i) op[i * DD] = f2bf(acc[i]);
        }
        __builtin_amdgcn_sched_barrier(0);
        __builtin_amdgcn_s_barrier();      // all waves done reading buf before re-stage
        __builtin_amdgcn_sched_barrier(0);
    }
#undef STAGE_CHUNK

    // ---- Phase 0 (post-loop): mod MLP -> decay/bgate; inject; border; RMW edits ----
    if (tid < 64) {
        s_cc[tid] = cell_context[bc * DD + tid];
        s_x[tid]  = x[(size_t)b * (NCC * DD) + c * DD + tid];
    }
    __syncthreads();
    if (tid < 64) {
        float acc = mod_b1[c * 64 + tid];
        const float* wp = mod_w1 + (size_t)c * 64 * 64 + tid;
        #pragma unroll
        for (int d = 0; d < 64; ++d) acc += s_cc[d] * wp[d * 64];
        s_hmod[tid] = tanh_fast(acc);
    }
    __syncthreads();
    if (tid < 5) {
        float acc = mod_b2[c * 5 + tid];
        const float* wp = mod_w2 + (size_t)c * 64 * 5 + tid;
        #pragma unroll
        for (int hh = 0; hh < 64; ++hh) acc += s_hmod[hh] * wp[hh * 5];
        s_mod[tid] = acc;
    }
    __syncthreads();
    if (tid < 256) {
        ws_decay[bc * NN + tid] = sigm(decay_logit[(size_t)bc * NN + tid] + s_mod[0]);
        if (tid < 4) s_bgate[tid] = sigm(border_gate_logit[bc * 4 + tid] + s_mod[1 + tid]);
    }
    __syncthreads();
    if (tid < 256) {
        const int grp = cell_to_group[c];
        float acc = inject_b[grp * 256 + tid];
        const float4* wv = (const float4*)(inject_w + ((size_t)grp * 256 + tid) * 64);
        #pragma unroll
        for (int i4 = 0; i4 < 16; ++i4) {
            const float4 v = wv[i4];
            acc += v.x * s_x[i4 * 4 + 0] + v.y * s_x[i4 * 4 + 1]
                 + v.z * s_x[i4 * 4 + 2] + v.w * s_x[i4 * 4 + 3];
        }
        s_inj[tid] = acc;
    } else {
        const int q = tid - 256, p = q >> 6, d = q & 63;
        const int gi = c >> 3, gj = c & 7;
        int cn = -1, ps = 0;
        if (p == 0)      { if (gi > 0) { cn = c - 8; ps = 1; } }
        else if (p == 1) { if (gi < 7) { cn = c + 8; ps = 0; } }
        else if (p == 2) { if (gj > 0) { cn = c - 1; ps = 3; } }
        else             { if (gj < 7) { cn = c + 1; ps = 2; } }
        s_bord[q] = (cn >= 0) ? s_bgate[p] * msg[(((size_t)b * NCC + cn) * NN + 8 + ps) * DD + d]
                              : 0.0f;
    }
    __syncthreads();
    if (tid < 256) {                       // RMW edits on rows 0..3 (inject), 8..11 (border)
        const int n = tid >> 6, d = tid & 63;
        unsigned short* base = ws_recv + (size_t)bc * NN * DD;
        unsigned short* p1 = base + n * DD + d;
        *p1 = f2bf(bf2f(*p1) + s_inj[tid]);
        unsigned short* p2 = base + (8 + n) * DD + d;
        *p2 = f2bf(bf2f(*p2) + s_bord[tid]);
    }
}

// ---------------- Kernel B: MLP chain per (b,c,tile-of-64) ----------------
// 4096 blocks x 256 threads. Waves split by COLUMNS so every weight fragment is
// loaded exactly once per block (160KB/block from L2).
extern "C" __global__ void __launch_bounds__(256,3)
mg_mlp(const float* __restrict__ h, const float* __restrict__ neuron_id,
       const float* __restrict__ state_b1, const float* __restrict__ state_b2,
       const float* __restrict__ msg_b1, const float* __restrict__ msg_b2,
       const unsigned short* __restrict__ sw1b, const unsigned short* __restrict__ sw2b,
       const unsigned short* __restrict__ mw1b, const unsigned short* __restrict__ mw2b,
       const unsigned short* __restrict__ ws_recv, const float* __restrict__ ws_decay,
       float* __restrict__ out_read, float* __restrict__ out_h, float* __restrict__ out_msg)
{
    __shared__ __align__(16) unsigned short s_hid[64*264];   // 33792 B
    __shared__ __align__(16) unsigned short s_h[64*72];      //  9216 B (h_new)
    __shared__ float s_mn[256];

    const int tid = threadIdx.x, lane = tid & 63, l15 = lane & 15, g = lane >> 4;
    const int wid = __builtin_amdgcn_readfirstlane(tid >> 6);
    const int bx = blockIdx.x, tile = bx & 3, bc = bx >> 2, b = bc >> 6, c = bc & 63;
    const int row0 = tile * 64;

    // A-fragments for all 4 row-tiles (recv bf16 direct; h f32 -> bf16 pack)
    s16x8 ar0[4], ar1[4], ah0[4], ah1[4];
    #pragma unroll
    for (int rt = 0; rt < 4; ++rt) {
        const unsigned short* rrow = ws_recv + ((size_t)bc * NN + row0 + 16 * rt + l15) * DD;
        ar0[rt] = *(const s16x8*)(rrow + 8 * g);
        ar1[rt] = *(const s16x8*)(rrow + 32 + 8 * g);
        const float* hrow = h + ((size_t)bc * NN + row0 + 16 * rt + l15) * DD;
        ah0[rt] = pack8(*(const float4*)(hrow + 8 * g),      *(const float4*)(hrow + 8 * g + 4));
        ah1[rt] = pack8(*(const float4*)(hrow + 32 + 8 * g), *(const float4*)(hrow + 36 + 8 * g));
    }

    // ---- Phase B: hid_s = tanh([recv|h] @ sw1^T + b1), cols [64*wid, 64*wid+64) ----
    #pragma unroll
    for (int cc = 0; cc < 4; ++cc) {
        const int n0 = 64 * wid + 16 * cc;
        const unsigned short* Bb = sw1b + (size_t)(n0 + l15) * 128;
        const s16x8 w0 = *(const s16x8*)(Bb + 8 * g);
        const s16x8 w1 = *(const s16x8*)(Bb + 32 + 8 * g);
        const s16x8 w2 = *(const s16x8*)(Bb + 64 + 8 * g);
        const s16x8 w3 = *(const s16x8*)(Bb + 96 + 8 * g);
        const float bias = state_b1[n0 + l15];
        #pragma unroll
        for (int rt = 0; rt < 4; ++rt) {
            f32x4 acc = {0.f, 0.f, 0.f, 0.f};
            acc = MFMA16(ar0[rt], w0, acc);
            acc = MFMA16(ar1[rt], w1, acc);
            acc = MFMA16(ah0[rt], w2, acc);
            acc = MFMA16(ah1[rt], w3, acc);
            #pragma unroll
            for (int i = 0; i < 4; ++i)
                s_hid[(16 * rt + 4 * g + i) * 264 + n0 + l15] = f2bf(tanh_fast(acc[i] + bias));
        }
    }
    __syncthreads();

    // ---- Phase C: cand + decay blend, cols [16*wid, 16*wid+16) ----
    {
        const int d0 = 16 * wid + l15;
        const unsigned short* B0 = sw2b + (size_t)d0 * 256;
        s16x8 wf[8];
        #pragma unroll
        for (int k = 0; k < 8; ++k) wf[k] = *(const s16x8*)(B0 + 32 * k + 8 * g);
        const float sb = state_b2[d0];
        #pragma unroll
        for (int rt = 0; rt < 4; ++rt) {
            f32x4 acc = {0.f, 0.f, 0.f, 0.f};
            #pragma unroll
            for (int k = 0; k < 8; ++k) {
                const s16x8 af = *(const s16x8*)&s_hid[(16 * rt + l15) * 264 + 32 * k + 8 * g];
                acc = MFMA16(af, wf[k], acc);
            }
            #pragma unroll
            for (int i = 0; i < 4; ++i) {
                const int lrow = 16 * rt + 4 * g + i, grow = row0 + lrow;
                const float dec = ws_decay[bc * NN + grow];
                const float hv  = h[((size_t)bc * NN + grow) * DD + d0];
                const float hn  = dec * hv + (1.0f - dec) * tanh_fast(acc[i] + sb);
                s_h[lrow * 72 + d0] = f2bf(hn);
                out_h[((size_t)bc * NN + grow) * DD + d0] = hn;
            }
        }
    }
    __syncthreads();

    // ---- Phase D: hid_m = tanh(h_new @ mw1^T + b1m), cols [64*wid, 64*wid+64) ----
    {
        s16x8 hn0[4], hn1[4];
        #pragma unroll
        for (int rt = 0; rt < 4; ++rt) {
            const int hr = (16 * rt + l15) * 72;
            hn0[rt] = *(const s16x8*)&s_h[hr + 8 * g];
            hn1[rt] = *(const s16x8*)&s_h[hr + 32 + 8 * g];
        }
        #pragma unroll
        for (int cc = 0; cc < 4; ++cc) {
            const int n0 = 64 * wid + 16 * cc;
            const unsigned short* Bb = mw1b + (size_t)(n0 + l15) * 64;
            const s16x8 w0 = *(const s16x8*)(Bb + 8 * g);
            const s16x8 w1 = *(const s16x8*)(Bb + 32 + 8 * g);
            const float bias = msg_b1[n0 + l15];
            #pragma unroll
            for (int rt = 0; rt < 4; ++rt) {
                f32x4 acc = {0.f, 0.f, 0.f, 0.f};
                acc = MFMA16(hn0[rt], w0, acc);
                acc = MFMA16(hn1[rt], w1, acc);
                #pragma unroll
                for (int i = 0; i < 4; ++i)
                    s_hid[(16 * rt + 4 * g + i) * 264 + n0 + l15] = f2bf(tanh_fast(acc[i] + bias));
            }
        }
    }
    __syncthreads();

    // ---- Phase E: msg_new = tanh(hid_m @ mw2^T + b2m) + neuron_id, cols [16*wid,+16) ----
    {
        const int d0 = 16 * wid + l15;
        const unsigned short* B0 = mw2b + (size_t)d0 * 256;
        s16x8 wf[8];
        #pragma unroll
        for (int k = 0; k < 8; ++k) wf[k] = *(const s16x8*)(B0 + 32 * k + 8 * g);
        const float mb = msg_b2[d0];
        #pragma unroll
        for (int rt = 0; rt < 4; ++rt) {
            f32x4 acc = {0.f, 0.f, 0.f, 0.f};
            #pragma unroll
            for (int k = 0; k < 8; ++k) {
                const s16x8 af = *(const s16x8*)&s_hid[(16 * rt + l15) * 264 + 32 * k + 8 * g];
                acc = MFMA16(af, wf[k], acc);
            }
            #pragma unroll
            for (int i = 0; i < 4; ++i) {
                const int lrow = 16 * rt + 4 * g + i, grow = row0 + lrow;
                const float m = tanh_fast(acc[i] + mb)
                              + neuron_id[((size_t)c * NN + grow) * DD + d0];
                out_msg[((size_t)bc * NN + grow) * DD + d0] = m;
                if (tile == 0 && lrow >= 4 && lrow < 8) s_mn[(lrow - 4) * 64 + d0] = m;
            }
        }
    }
    __syncthreads();
    if (tile == 0 && tid < 64)
        out_read[(size_t)b * (NCC * DD) + c * 64 + tid] =
            0.25f * (s_mn[tid] + s_mn[64 + tid] + s_mn[128 + tid] + s_mn[192 + tid]);
}

extern "C" void kernel_launch(void* const* d_in, const int* in_sizes, int n_in,
                              void* d_out, int out_size, void* d_ws, size_t ws_size,
                              hipStream_t stream) {
    (void)in_sizes; (void)n_in; (void)ws_size; (void)out_size;
    const float* x                 = (const float*)d_in[0];
    const float* h                 = (const float*)d_in[1];
    const float* msg               = (const float*)d_in[2];
    const float* W                 = (const float*)d_in[3];
    const float* decay_logit       = (const float*)d_in[4];
    const float* cell_context      = (const float*)d_in[5];
    const float* border_gate_logit = (const float*)d_in[6];
    const float* neuron_id         = (const float*)d_in[7];
    const float* state_w1          = (const float*)d_in[8];
    const float* state_b1          = (const float*)d_in[9];
    const float* state_w2          = (const float*)d_in[10];
    const float* state_b2          = (const float*)d_in[11];
    const float* msg_w1            = (const float*)d_in[12];
    const float* msg_b1            = (const float*)d_in[13];
    const float* msg_w2            = (const float*)d_in[14];
    const float* msg_b2            = (const float*)d_in[15];
    const float* inject_w          = (const float*)d_in[16];
    const float* inject_b          = (const float*)d_in[17];
    const float* mod_w1            = (const float*)d_in[18];
    const float* mod_b1            = (const float*)d_in[19];
    const float* mod_w2            = (const float*)d_in[20];
    const float* mod_b2            = (const float*)d_in[21];
    const int*   cell_to_group     = (const int*)d_in[22];

    float* out_read = (float*)d_out;
    float* out_h    = out_read + (size_t)BB * NCC * DD;
    float* out_msg  = out_h + (size_t)BB * NCC * NN * DD;

    // ws layout (bytes): [0,163840) bf16 weights | [163840,1212416) decay f32
    //                    | [1212416,34766848) recv bf16
    unsigned short* ws16   = (unsigned short*)d_ws;
    unsigned short* sw1b   = ws16;
    unsigned short* sw2b   = ws16 + 32768;
    unsigned short* mw1b   = ws16 + 49152;
    unsigned short* mw2b   = ws16 + 65536;
    float*          ws_dec = (float*)((char*)d_ws + 163840);
    unsigned short* ws_rcv = (unsigned short*)((char*)d_ws + 1212416);

    hipLaunchKernelGGL(wconv, dim3(320), dim3(256), 0, stream,
                       state_w1, state_w2, msg_w1, msg_w2, ws16);

    hipLaunchKernelGGL(mg_recv, dim3(BB * NCC), dim3(512), 0, stream,
                       x, msg, W, decay_logit, cell_context, border_gate_logit,
                       inject_w, inject_b, mod_w1, mod_b1, mod_w2, mod_b2,
                       cell_to_group, ws_rcv, ws_dec);

    hipLaunchKernelGGL(mg_mlp, dim3(BB * NCC * 4), dim3(256), 0, stream,
                       h, neuron_id, state_b1, state_b2, msg_b1, msg_b2,
                       sw1b, sw2b, mw1b, mw2b, ws_rcv, ws_dec,
                       out_read, out_h, out_msg);
}

// Round 6
// 242.808 us; speedup vs baseline: 13.9302x; 1.0568x over previous
//
#include <hip/hip_runtime.h>
#include <math.h>

#define BB 16
#define NCC 64
#define NN 256
#define DD 64

typedef short s16x8 __attribute__((ext_vector_type(8)));
typedef float f32x4 __attribute__((ext_vector_type(4)));

#define MFMA16(a,b,c) __builtin_amdgcn_mfma_f32_16x16x32_bf16((a),(b),(c),0,0,0)

__device__ __forceinline__ unsigned short f2bf(float f){
    union{float f;unsigned u;}v; v.f=f;
    unsigned r = v.u + 0x7FFFu + ((v.u>>16)&1u);   // RNE
    return (unsigned short)(r>>16);
}
__device__ __forceinline__ float bf2f(unsigned short s){
    union{unsigned u;float f;}v; v.u=((unsigned)s)<<16; return v.f;
}
// v_cvt_pk_bf16_f32: no builtin on gfx950 -> inline asm (T12 recipe)
__device__ __forceinline__ unsigned cvt2(float a,float b){
    unsigned r;
    asm("v_cvt_pk_bf16_f32 %0, %1, %2" : "=v"(r) : "v"(a), "v"(b));
    return r;
}
__device__ __forceinline__ unsigned short cvt1(float a){   // 1-op f32->bf16 RNE
    unsigned r;
    asm("v_cvt_pk_bf16_f32 %0, %1, %2" : "=v"(r) : "v"(a), "v"(a));
    return (unsigned short)r;
}
__device__ __forceinline__ s16x8 pack8(float4 lo,float4 hi){
    union{unsigned u[4];s16x8 v;}r;
    r.u[0]=cvt2(lo.x,lo.y); r.u[1]=cvt2(lo.z,lo.w);
    r.u[2]=cvt2(hi.x,hi.y); r.u[3]=cvt2(hi.z,hi.w);
    return r.v;
}
// tanh = 1 - 2/(exp2(x*2/ln2)+1): saturates correctly at +-inf, no clamp needed
__device__ __forceinline__ float tanh2(float x){
    float e = __builtin_amdgcn_exp2f(x * 2.8853900817779268f);
    return 1.0f - 2.0f * __builtin_amdgcn_rcpf(e + 1.0f);
}
__device__ __forceinline__ float sigm(float v){ return __builtin_amdgcn_rcpf(1.0f+__expf(-v)); }

// ---------------- weight f32 -> bf16 prep ----------------
extern "C" __global__ void __launch_bounds__(256)
wconv(const float* __restrict__ sw1, const float* __restrict__ sw2,
      const float* __restrict__ mw1, const float* __restrict__ mw2,
      unsigned short* __restrict__ ws)
{
    const int i = blockIdx.x * 256 + threadIdx.x;
    float v;
    if (i < 32768)      v = sw1[i];
    else if (i < 49152) v = sw2[i - 32768];
    else if (i < 65536) v = mw1[i - 49152];
    else                v = mw2[i - 65536];
    ws[i] = f2bf(v);
}

// ---------------- Kernel A: recv = W@msg (+ mod MLP, inject, border edits) ----------------
// ROUND-4 PROVEN STRUCTURE: one block per (b,c), 512 threads, separate s_msgT,
// W streamed via global_load_lds double-buffer, counted vmcnt(4) + raw s_barrier.
extern "C" __global__ void __launch_bounds__(512,2)
mg_recv(const float* __restrict__ x, const float* __restrict__ msg,
        const float* __restrict__ W, const float* __restrict__ decay_logit,
        const float* __restrict__ cell_context, const float* __restrict__ border_gate_logit,
        const float* __restrict__ inject_w, const float* __restrict__ inject_b,
        const float* __restrict__ mod_w1, const float* __restrict__ mod_b1,
        const float* __restrict__ mod_w2, const float* __restrict__ mod_b2,
        const int* __restrict__ cell_to_group,
        unsigned short* __restrict__ ws_recv, float* __restrict__ ws_decay)
{
    __shared__ __align__(16) float s_w[2][32*260];            // 66560 B, pitch 260 f32
    __shared__ __align__(16) unsigned short s_msgT[64*264];   // 33792 B
    __shared__ float s_x[64], s_cc[64], s_hmod[64], s_mod[8], s_bgate[4];
    __shared__ float s_inj[256], s_bord[256];

    const int tid  = threadIdx.x;
    const int lane = tid & 63;
    const int l15  = lane & 15;
    const int g    = lane >> 4;
    const int wid  = __builtin_amdgcn_readfirstlane(tid >> 6);
    const int bc   = blockIdx.x;
    const int b    = bc >> 6;
    const int c    = bc & 63;
    const float* Wb = W + (size_t)bc * NN * NN;

#define STAGE_CHUNK(n) do{                                                            \
    const int _buf=(n)&1;                                                             \
    _Pragma("unroll")                                                                 \
    for(int _j=0;_j<4;++_j){                                                          \
        const int _row=4*wid+_j;                                                      \
        const float* _gp = Wb + (size_t)(32*(n)+_row)*NN + lane*4;                    \
        __builtin_amdgcn_global_load_lds(                                             \
            (const __attribute__((address_space(1))) void*)_gp,                       \
            (__attribute__((address_space(3))) void*)&s_w[_buf][_row*260], 16, 0, 0); \
    }                                                                                 \
}while(0)

    // deep-queue prefetch of W chunks 0 and 1 (8 x 1KB wave-loads in flight)
    STAGE_CHUNK(0);
    STAGE_CHUNK(1);

    // msg -> LDS transposed bf16 (msgT[d][m], pitch 264) -- overlaps W flight
    for (int it = tid; it < 2048; it += 512) {
        const int d4 = it & 15, mp = it >> 4;
        const float* src = msg + ((size_t)bc * NN + mp * 2) * DD + d4 * 4;
        const float4 v0 = *(const float4*)(src);
        const float4 v1 = *(const float4*)(src + DD);
        const float* p0 = &v0.x; const float* p1 = &v1.x;
        #pragma unroll
        for (int j = 0; j < 4; ++j)
            *(unsigned*)&s_msgT[(d4 * 4 + j) * 264 + mp * 2] = cvt2(p0[j], p1[j]);
    }

    asm volatile("s_waitcnt lgkmcnt(0)" ::: "memory");
    __builtin_amdgcn_sched_barrier(0);
    __builtin_amdgcn_s_barrier();          // msgT visible to all waves
    __builtin_amdgcn_sched_barrier(0);

    const int rt = wid & 1, ct = wid >> 1;
    for (int rc = 0; rc < 8; ++rc) {
        if (rc >= 1 && rc <= 6) STAGE_CHUNK(rc + 1);
        if (rc < 7) asm volatile("s_waitcnt vmcnt(4)" ::: "memory");
        else        asm volatile("s_waitcnt vmcnt(0)" ::: "memory");
        __builtin_amdgcn_sched_barrier(0);
        __builtin_amdgcn_s_barrier();      // chunk rc landed (all waves)
        __builtin_amdgcn_sched_barrier(0);
        {
            const float* wrow = &s_w[rc & 1][(16 * rt + l15) * 260];
            const unsigned short* brow = &s_msgT[(16 * ct + l15) * 264];
            f32x4 acc = {0.f, 0.f, 0.f, 0.f};
            #pragma unroll
            for (int k = 0; k < 8; ++k) {
                const float4 w0 = *(const float4*)(wrow + 32 * k + 8 * g);
                const float4 w1 = *(const float4*)(wrow + 32 * k + 8 * g + 4);
                const s16x8 bf = *(const s16x8*)(brow + 32 * k + 8 * g);
                acc = MFMA16(pack8(w0, w1), bf, acc);
            }
            const int rowb = 32 * rc + 16 * rt + 4 * g;
            unsigned short* op = ws_recv + ((size_t)bc * NN + rowb) * DD + 16 * ct + l15;
            #pragma unroll
            for (int i = 0; i < 4; ++i) op[i * DD] = cvt1(acc[i]);
        }
        __builtin_amdgcn_sched_barrier(0);
        __builtin_amdgcn_s_barrier();      // all waves done reading buf before re-stage
        __builtin_amdgcn_sched_barrier(0);
    }
#undef STAGE_CHUNK

    // ---- post-loop: mod MLP -> decay/bgate; inject; border; RMW edits ----
    if (tid < 64) {
        s_cc[tid] = cell_context[bc * DD + tid];
        s_x[tid]  = x[(size_t)b * (NCC * DD) + c * DD + tid];
    }
    __syncthreads();
    if (tid < 64) {
        float acc = mod_b1[c * 64 + tid];
        const float* wp = mod_w1 + (size_t)c * 64 * 64 + tid;
        #pragma unroll
        for (int d = 0; d < 64; ++d) acc += s_cc[d] * wp[d * 64];
        s_hmod[tid] = tanh2(acc);
    }
    __syncthreads();
    if (tid < 5) {
        float acc = mod_b2[c * 5 + tid];
        const float* wp = mod_w2 + (size_t)c * 64 * 5 + tid;
        #pragma unroll
        for (int hh = 0; hh < 64; ++hh) acc += s_hmod[hh] * wp[hh * 5];
        s_mod[tid] = acc;
    }
    __syncthreads();
    if (tid < 256) {
        ws_decay[bc * NN + tid] = sigm(decay_logit[(size_t)bc * NN + tid] + s_mod[0]);
        if (tid < 4) s_bgate[tid] = sigm(border_gate_logit[bc * 4 + tid] + s_mod[1 + tid]);
    }
    __syncthreads();
    if (tid < 256) {
        const int grp = cell_to_group[c];
        float acc = inject_b[grp * 256 + tid];
        const float4* wv = (const float4*)(inject_w + ((size_t)grp * 256 + tid) * 64);
        #pragma unroll
        for (int i4 = 0; i4 < 16; ++i4) {
            const float4 v = wv[i4];
            acc += v.x * s_x[i4 * 4 + 0] + v.y * s_x[i4 * 4 + 1]
                 + v.z * s_x[i4 * 4 + 2] + v.w * s_x[i4 * 4 + 3];
        }
        s_inj[tid] = acc;
    } else {
        const int q = tid - 256, p = q >> 6, d = q & 63;
        const int gi = c >> 3, gj = c & 7;
        int cn = -1, ps = 0;
        if (p == 0)      { if (gi > 0) { cn = c - 8; ps = 1; } }
        else if (p == 1) { if (gi < 7) { cn = c + 8; ps = 0; } }
        else if (p == 2) { if (gj > 0) { cn = c - 1; ps = 3; } }
        else             { if (gj < 7) { cn = c + 1; ps = 2; } }
        s_bord[q] = (cn >= 0) ? s_bgate[p] * msg[(((size_t)b * NCC + cn) * NN + 8 + ps) * DD + d]
                              : 0.0f;
    }
    __syncthreads();
    if (tid < 256) {                       // RMW edits rows 0..3 (inject), 8..11 (border)
        const int n = tid >> 6, d = tid & 63;
        unsigned short* base = ws_recv + (size_t)bc * NN * DD;
        unsigned short* p1 = base + n * DD + d;
        *p1 = f2bf(bf2f(*p1) + s_inj[tid]);
        unsigned short* p2 = base + (8 + n) * DD + d;
        *p2 = f2bf(bf2f(*p2) + s_bord[tid]);
    }
}

// ---------------- Kernel B: MLP chain per (b,c,tile-of-64) ----------------
// 4096 blocks x 256 threads, 3 blocks/CU. Waves split by COLUMNS; all weight
// fragments for each phase batched into registers upfront (hide L2 latency).
extern "C" __global__ void __launch_bounds__(256,3)
mg_mlp(const float* __restrict__ h, const float* __restrict__ neuron_id,
       const float* __restrict__ state_b1, const float* __restrict__ state_b2,
       const float* __restrict__ msg_b1, const float* __restrict__ msg_b2,
       const unsigned short* __restrict__ sw1b, const unsigned short* __restrict__ sw2b,
       const unsigned short* __restrict__ mw1b, const unsigned short* __restrict__ mw2b,
       const unsigned short* __restrict__ ws_recv, const float* __restrict__ ws_decay,
       float* __restrict__ out_read, float* __restrict__ out_h, float* __restrict__ out_msg)
{
    __shared__ __align__(16) unsigned short s_hid[64*264];   // 33792 B
    __shared__ __align__(16) unsigned short s_h[64*72];      //  9216 B (h_new)
    __shared__ float s_mn[256];

    const int tid = threadIdx.x, lane = tid & 63, l15 = lane & 15, g = lane >> 4;
    const int wid = __builtin_amdgcn_readfirstlane(tid >> 6);
    const int bx = blockIdx.x, tile = bx & 3, bc = bx >> 2, b = bc >> 6, c = bc & 63;
    const int row0 = tile * 64;

    // ---- batched loads: A-fragments + ALL phase-B weight fragments ----
    s16x8 ar0[4], ar1[4], ah0[4], ah1[4];
    #pragma unroll
    for (int rt = 0; rt < 4; ++rt) {
        const unsigned short* rrow = ws_recv + ((size_t)bc * NN + row0 + 16 * rt + l15) * DD;
        ar0[rt] = *(const s16x8*)(rrow + 8 * g);
        ar1[rt] = *(const s16x8*)(rrow + 32 + 8 * g);
        const float* hrow = h + ((size_t)bc * NN + row0 + 16 * rt + l15) * DD;
        ah0[rt] = pack8(*(const float4*)(hrow + 8 * g),      *(const float4*)(hrow + 8 * g + 4));
        ah1[rt] = pack8(*(const float4*)(hrow + 32 + 8 * g), *(const float4*)(hrow + 36 + 8 * g));
    }
    s16x8 wB[16];
    float biasB[4];
    #pragma unroll
    for (int cc = 0; cc < 4; ++cc) {
        const unsigned short* Bb = sw1b + (size_t)(64 * wid + 16 * cc + l15) * 128;
        wB[cc * 4 + 0] = *(const s16x8*)(Bb + 8 * g);
        wB[cc * 4 + 1] = *(const s16x8*)(Bb + 32 + 8 * g);
        wB[cc * 4 + 2] = *(const s16x8*)(Bb + 64 + 8 * g);
        wB[cc * 4 + 3] = *(const s16x8*)(Bb + 96 + 8 * g);
        biasB[cc] = state_b1[64 * wid + 16 * cc + l15];
    }

    // ---- Phase B: hid_s = tanh([recv|h] @ sw1^T + b1), cols [64*wid, +64) ----
    #pragma unroll
    for (int cc = 0; cc < 4; ++cc) {
        const int n0 = 64 * wid + 16 * cc;
        #pragma unroll
        for (int rt = 0; rt < 4; ++rt) {
            f32x4 acc = {0.f, 0.f, 0.f, 0.f};
            acc = MFMA16(ar0[rt], wB[cc * 4 + 0], acc);
            acc = MFMA16(ar1[rt], wB[cc * 4 + 1], acc);
            acc = MFMA16(ah0[rt], wB[cc * 4 + 2], acc);
            acc = MFMA16(ah1[rt], wB[cc * 4 + 3], acc);
            #pragma unroll
            for (int i = 0; i < 4; ++i)
                s_hid[(16 * rt + 4 * g + i) * 264 + n0 + l15] = cvt1(tanh2(acc[i] + biasB[cc]));
        }
    }
    __syncthreads();

    // ---- Phase C: cand + decay blend, cols [16*wid, +16) ----
    {
        const int d0 = 16 * wid + l15;
        const unsigned short* B0 = sw2b + (size_t)d0 * 256;
        s16x8 wf[8];
        #pragma unroll
        for (int k = 0; k < 8; ++k) wf[k] = *(const s16x8*)(B0 + 32 * k + 8 * g);
        const float sb = state_b2[d0];
        float hvv[16], dcc[16];
        #pragma unroll
        for (int rt = 0; rt < 4; ++rt)
            #pragma unroll
            for (int i = 0; i < 4; ++i) {
                const int grow = row0 + 16 * rt + 4 * g + i;
                hvv[rt * 4 + i] = h[((size_t)bc * NN + grow) * DD + d0];
                dcc[rt * 4 + i] = ws_decay[bc * NN + grow];
            }
        #pragma unroll
        for (int rt = 0; rt < 4; ++rt) {
            f32x4 acc = {0.f, 0.f, 0.f, 0.f};
            #pragma unroll
            for (int k = 0; k < 8; ++k) {
                const s16x8 af = *(const s16x8*)&s_hid[(16 * rt + l15) * 264 + 32 * k + 8 * g];
                acc = MFMA16(af, wf[k], acc);
            }
            #pragma unroll
            for (int i = 0; i < 4; ++i) {
                const int lrow = 16 * rt + 4 * g + i, grow = row0 + lrow;
                const float dec = dcc[rt * 4 + i];
                const float hn  = dec * hvv[rt * 4 + i] + (1.0f - dec) * tanh2(acc[i] + sb);
                s_h[lrow * 72 + d0] = cvt1(hn);
                out_h[((size_t)bc * NN + grow) * DD + d0] = hn;
            }
        }
    }
    __syncthreads();

    // ---- Phase D: hid_m = tanh(h_new @ mw1^T + b1m), cols [64*wid, +64) ----
    {
        s16x8 hn0[4], hn1[4];
        #pragma unroll
        for (int rt = 0; rt < 4; ++rt) {
            const int hr = (16 * rt + l15) * 72;
            hn0[rt] = *(const s16x8*)&s_h[hr + 8 * g];
            hn1[rt] = *(const s16x8*)&s_h[hr + 32 + 8 * g];
        }
        s16x8 wD[8];
        float biasD[4];
        #pragma unroll
        for (int cc = 0; cc < 4; ++cc) {
            const unsigned short* Bb = mw1b + (size_t)(64 * wid + 16 * cc + l15) * 64;
            wD[cc * 2 + 0] = *(const s16x8*)(Bb + 8 * g);
            wD[cc * 2 + 1] = *(const s16x8*)(Bb + 32 + 8 * g);
            biasD[cc] = msg_b1[64 * wid + 16 * cc + l15];
        }
        #pragma unroll
        for (int cc = 0; cc < 4; ++cc) {
            const int n0 = 64 * wid + 16 * cc;
            #pragma unroll
            for (int rt = 0; rt < 4; ++rt) {
                f32x4 acc = {0.f, 0.f, 0.f, 0.f};
                acc = MFMA16(hn0[rt], wD[cc * 2 + 0], acc);
                acc = MFMA16(hn1[rt], wD[cc * 2 + 1], acc);
                #pragma unroll
                for (int i = 0; i < 4; ++i)
                    s_hid[(16 * rt + 4 * g + i) * 264 + n0 + l15] = cvt1(tanh2(acc[i] + biasD[cc]));
            }
        }
    }
    __syncthreads();

    // ---- Phase E: msg_new = tanh(hid_m @ mw2^T + b2m) + neuron_id, cols [16*wid, +16) ----
    {
        const int d0 = 16 * wid + l15;
        const unsigned short* B0 = mw2b + (size_t)d0 * 256;
        s16x8 wf[8];
        #pragma unroll
        for (int k = 0; k < 8; ++k) wf[k] = *(const s16x8*)(B0 + 32 * k + 8 * g);
        const float mb = msg_b2[d0];
        float nid[16];
        #pragma unroll
        for (int rt = 0; rt < 4; ++rt)
            #pragma unroll
            for (int i = 0; i < 4; ++i)
                nid[rt * 4 + i] = neuron_id[((size_t)c * NN + row0 + 16 * rt + 4 * g + i) * DD + d0];
        #pragma unroll
        for (int rt = 0; rt < 4; ++rt) {
            f32x4 acc = {0.f, 0.f, 0.f, 0.f};
            #pragma unroll
            for (int k = 0; k < 8; ++k) {
                const s16x8 af = *(const s16x8*)&s_hid[(16 * rt + l15) * 264 + 32 * k + 8 * g];
                acc = MFMA16(af, wf[k], acc);
            }
            #pragma unroll
            for (int i = 0; i < 4; ++i) {
                const int lrow = 16 * rt + 4 * g + i, grow = row0 + lrow;
                const float m = tanh2(acc[i] + mb) + nid[rt * 4 + i];
                out_msg[((size_t)bc * NN + grow) * DD + d0] = m;
                if (tile == 0 && lrow >= 4 && lrow < 8) s_mn[(lrow - 4) * 64 + d0] = m;
            }
        }
    }
    __syncthreads();
    if (tile == 0 && tid < 64)
        out_read[(size_t)b * (NCC * DD) + c * 64 + tid] =
            0.25f * (s_mn[tid] + s_mn[64 + tid] + s_mn[128 + tid] + s_mn[192 + tid]);
}

extern "C" void kernel_launch(void* const* d_in, const int* in_sizes, int n_in,
                              void* d_out, int out_size, void* d_ws, size_t ws_size,
                              hipStream_t stream) {
    (void)in_sizes; (void)n_in; (void)ws_size; (void)out_size;
    const float* x                 = (const float*)d_in[0];
    const float* h                 = (const float*)d_in[1];
    const float* msg               = (const float*)d_in[2];
    const float* W                 = (const float*)d_in[3];
    const float* decay_logit       = (const float*)d_in[4];
    const float* cell_context      = (const float*)d_in[5];
    const float* border_gate_logit = (const float*)d_in[6];
    const float* neuron_id         = (const float*)d_in[7];
    const float* state_w1          = (const float*)d_in[8];
    const float* state_b1          = (const float*)d_in[9];
    const float* state_w2          = (const float*)d_in[10];
    const float* state_b2          = (const float*)d_in[11];
    const float* msg_w1            = (const float*)d_in[12];
    const float* msg_b1            = (const float*)d_in[13];
    const float* msg_w2            = (const float*)d_in[14];
    const float* msg_b2            = (const float*)d_in[15];
    const float* inject_w          = (const float*)d_in[16];
    const float* inject_b          = (const float*)d_in[17];
    const float* mod_w1            = (const float*)d_in[18];
    const float* mod_b1            = (const float*)d_in[19];
    const float* mod_w2            = (const float*)d_in[20];
    const float* mod_b2            = (const float*)d_in[21];
    const int*   cell_to_group     = (const int*)d_in[22];

    float* out_read = (float*)d_out;
    float* out_h    = out_read + (size_t)BB * NCC * DD;
    float* out_msg  = out_h + (size_t)BB * NCC * NN * DD;

    // ws layout (bytes): [0,163840) bf16 weights | [163840,1212416) decay f32
    //                    | [1212416,34766848) recv bf16
    unsigned short* ws16   = (unsigned short*)d_ws;
    unsigned short* sw1b   = ws16;
    unsigned short* sw2b   = ws16 + 32768;
    unsigned short* mw1b   = ws16 + 49152;
    unsigned short* mw2b   = ws16 + 65536;
    float*          ws_dec = (float*)((char*)d_ws + 163840);
    unsigned short* ws_rcv = (unsigned short*)((char*)d_ws + 1212416);

    hipLaunchKernelGGL(wconv, dim3(320), dim3(256), 0, stream,
                       state_w1, state_w2, msg_w1, msg_w2, ws16);

    hipLaunchKernelGGL(mg_recv, dim3(BB * NCC), dim3(512), 0, stream,
                       x, msg, W, decay_logit, cell_context, border_gate_logit,
                       inject_w, inject_b, mod_w1, mod_b1, mod_w2, mod_b2,
                       cell_to_group, ws_rcv, ws_dec);

    hipLaunchKernelGGL(mg_mlp, dim3(BB * NCC * 4), dim3(256), 0, stream,
                       h, neuron_id, state_b1, state_b2, msg_b1, msg_b2,
                       sw1b, sw2b, mw1b, mw2b, ws_rcv, ws_dec,
                       out_read, out_h, out_msg);
}